// Round 2
// baseline (652.178 us; speedup 1.0000x reference)
//
#include <hip/hip_runtime.h>
#include <hip/hip_bf16.h>

// PointSelfAttention: B=1024 molecules x K=64 pts, hidden=512, H=8 heads, D=64
// R2: pre-convert h -> bf16 once; k_attn stages via int4 copies (no per-block f2bf);
// agg passed as bf16 through workspace to k_proj. Fallback to R1 path if ws too small.

#define HID 512
#define TBL 2048
#define DMAX 12.0f

typedef __attribute__((ext_vector_type(4))) float f32x4;
typedef __attribute__((ext_vector_type(8))) short bhalf8;

__device__ __forceinline__ short f2bf(float f) {
    union { float f; unsigned u; } x; x.f = f;
    unsigned u = x.u;
    unsigned r = (u + 0x7FFFu + ((u >> 16) & 1u)) >> 16;  // RNE
    return (short)r;
}

// ---- prep: transpose weights to bf16 [cols][K] so MFMA B-frags read contiguous K ----
__global__ __launch_bounds__(256) void k_prep_w(const float* __restrict__ w_qkv,
                                                const float* __restrict__ w_out,
                                                short* __restrict__ wqT,
                                                short* __restrict__ woT) {
    __shared__ short tile[64][68];
    const int t = threadIdx.x;
    int bt = blockIdx.x;
    const float* src; short* dst; int sld, tk, tc;
    if (bt < 192) { src = w_qkv; dst = wqT; sld = 1536; tk = bt & 7; tc = bt >> 3; }
    else { int b2 = bt - 192; src = w_out; dst = woT; sld = 512; tk = b2 & 7; tc = b2 >> 3; }
#pragma unroll
    for (int p = 0; p < 4; ++p) {
        int s = t + 256 * p;
        int r = s >> 4, sg = s & 15;
        const float4 v = *(const float4*)(src + (tk * 64 + r) * sld + tc * 64 + sg * 4);
        tile[r][sg * 4 + 0] = f2bf(v.x);
        tile[r][sg * 4 + 1] = f2bf(v.y);
        tile[r][sg * 4 + 2] = f2bf(v.z);
        tile[r][sg * 4 + 3] = f2bf(v.w);
    }
    __syncthreads();
#pragma unroll
    for (int p = 0; p < 16; ++p) {
        int o = t + 256 * p;
        int c = o >> 6, k = o & 63;
        dst[(tc * 64 + c) * 512 + tk * 64 + k] = tile[k][c];
    }
}

// ---- prep: h (fp32) -> bf16 once, shared by all 8 head-blocks per molecule ----
__global__ __launch_bounds__(256) void k_prep_h(const float* __restrict__ h,
                                                short* __restrict__ hbf) {
    int i = (blockIdx.x * 256 + threadIdx.x) * 8;
    float4 a = *(const float4*)(h + i);
    float4 b = *(const float4*)(h + i + 4);
    short sh[8];
    sh[0] = f2bf(a.x); sh[1] = f2bf(a.y); sh[2] = f2bf(a.z); sh[3] = f2bf(a.w);
    sh[4] = f2bf(b.x); sh[5] = f2bf(b.y); sh[6] = f2bf(b.z); sh[7] = f2bf(b.w);
    *(int4*)(hbf + i) = *(int4*)sh;
}

// ---- prep: per-head bias(d) table ----
__global__ __launch_bounds__(256) void k_prep_tbl(const float* __restrict__ centers,
                                                  const float* __restrict__ w_rbf,
                                                  const float* __restrict__ b_rbf,
                                                  float* __restrict__ tbl) {
    int idx = blockIdx.x * 256 + threadIdx.x;   // 8 heads * 2048
    int hh = idx >> 11, i = idx & (TBL - 1);
    float d = (float)i * (DMAX / (float)(TBL - 1));
    float s = b_rbf[hh];
    const float invw = 1.0f / 0.0625f;          // width = (8/32)^2
#pragma unroll 4
    for (int r = 0; r < 32; ++r) {
        float tt = d - centers[r];
        s += w_rbf[r * 8 + hh] * expf(-(tt * tt) * invw);
    }
    tbl[idx] = s;
}

// ---- kernel 1: per (molecule, head): QKV -> biased attention -> agg ----
// FAST=1: stage h from bf16 (int4 copies), write agg bf16 to ws.
// FAST=0: R1 path (fp32 h with f2bf, fp32 agg into d_out).
template <int FAST>
__global__ __launch_bounds__(256) void k_attn(const float* __restrict__ h,
                                              const short* __restrict__ hbf,
                                              const float* __restrict__ pos,
                                              const float* __restrict__ b_qkv,
                                              const short* __restrict__ wqT,
                                              const float* __restrict__ tbl,
                                              float* __restrict__ aggf,
                                              short* __restrict__ aggb) {
    __shared__ __align__(16) short u0[64 * 72];    // h chunk, later q (scaled)
    __shared__ __align__(16) short u1[192 * 72];   // w chunk, later k | v^T | P
    __shared__ float s_px[64], s_py[64], s_pz[64];
    __shared__ float s_tbl[TBL];

    const int bid = blockIdx.x;
    const int mol = bid >> 3, head = bid & 7;
    const int t = threadIdx.x;
    const int wave = t >> 6, lane = t & 63;
    const int l16 = lane & 15, g = lane >> 4;
    const int rowbase = mol * 64;

    for (int i = t; i < TBL; i += 256) s_tbl[i] = tbl[head * TBL + i];
    if (t < 64) {
        s_px[t] = pos[(rowbase + t) * 3 + 0];
        s_py[t] = pos[(rowbase + t) * 3 + 1];
        s_pz[t] = pos[(rowbase + t) * 3 + 2];
    }

    f32x4 acc[12];
#pragma unroll
    for (int i = 0; i < 12; ++i) acc[i] = (f32x4){0.f, 0.f, 0.f, 0.f};

    // ---- QKV GEMM: C[64 rows x 192 cols(q|k|v)] over K=512 in chunks of 64 ----
    for (int kc = 0; kc < 8; ++kc) {
        const int kb = kc * 64;
        if (FAST) {
#pragma unroll
            for (int p = 0; p < 2; ++p) {       // h chunk bf16: pure int4 copy
                int s = t + 256 * p;
                int row = s >> 3, seg = s & 7;
                *(int4*)(&u0[row * 72 + seg * 8]) =
                    *(const int4*)(hbf + (rowbase + row) * HID + kb + seg * 8);
            }
        } else {
#pragma unroll
            for (int p = 0; p < 4; ++p) {       // h chunk fp32 -> bf16
                int s = t + 256 * p;
                int row = s >> 4, seg = s & 15;
                const float4 v = *(const float4*)(h + (rowbase + row) * HID + kb + seg * 4);
                short4 b4;
                b4.x = f2bf(v.x); b4.y = f2bf(v.y); b4.z = f2bf(v.z); b4.w = f2bf(v.w);
                *(short4*)(&u0[row * 72 + seg * 4]) = b4;
            }
        }
#pragma unroll
        for (int p = 0; p < 6; ++p) {           // wT chunk [192 cols][64 k] bf16
            int s = t + 256 * p;
            int c = s >> 3, kq = s & 7;
            int sec = c >> 6, cc = c & 63;
            int gc = sec * 512 + head * 64 + cc;
            *(int4*)(&u1[c * 72 + kq * 8]) = *(const int4*)(wqT + gc * HID + kb + kq * 8);
        }
        __syncthreads();
        const int arow = wave * 16 + l16;
#pragma unroll
        for (int kk = 0; kk < 2; ++kk) {
            bhalf8 a = *(const bhalf8*)(&u0[arow * 72 + kk * 32 + g * 8]);
#pragma unroll
            for (int ct = 0; ct < 12; ++ct) {
                bhalf8 b = *(const bhalf8*)(&u1[(ct * 16 + l16) * 72 + kk * 32 + g * 8]);
                acc[ct] = __builtin_amdgcn_mfma_f32_16x16x32_bf16(a, b, acc[ct], 0, 0, 0);
            }
        }
        __syncthreads();
    }

    // ---- stage q (x scale, exact pow2) / k / v^T to LDS, + b_qkv ----
    const int r0 = wave * 16 + g * 4;
#pragma unroll
    for (int ct = 0; ct < 12; ++ct) {
        int c = ct * 16 + l16;
        int sec = c >> 6, cc = c & 63;          // sec uniform per ct (unrolled)
        float bv = b_qkv[sec * 512 + head * 64 + cc];
#pragma unroll
        for (int r = 0; r < 4; ++r) {
            float val = acc[ct][r] + bv;
            if (sec == 0)      u0[(r0 + r) * 72 + cc] = f2bf(val * 0.125f);
            else if (sec == 1) u1[(r0 + r) * 72 + cc] = f2bf(val);
            else               u1[4608 + cc * 72 + (r0 + r)] = f2bf(val);   // v^T
        }
    }
    __syncthreads();

    // ---- S = q_scaled . k^T  (wave owns rows wave*16..+15) ----
    f32x4 sacc[4];
#pragma unroll
    for (int i = 0; i < 4; ++i) sacc[i] = (f32x4){0.f, 0.f, 0.f, 0.f};
    const int srow = wave * 16 + l16;
#pragma unroll
    for (int kk = 0; kk < 2; ++kk) {
        bhalf8 a = *(const bhalf8*)(&u0[srow * 72 + kk * 32 + g * 8]);
#pragma unroll
        for (int ct = 0; ct < 4; ++ct) {
            bhalf8 b = *(const bhalf8*)(&u1[(ct * 16 + l16) * 72 + kk * 32 + g * 8]);
            sacc[ct] = __builtin_amdgcn_mfma_f32_16x16x32_bf16(a, b, sacc[ct], 0, 0, 0);
        }
    }

    // ---- + RBF bias via table lookup ----
    const float tscale = (float)(TBL - 1) / DMAX;
#pragma unroll
    for (int ct = 0; ct < 4; ++ct) {
        int col = ct * 16 + l16;
        float cx = s_px[col], cy = s_py[col], cz = s_pz[col];
#pragma unroll
        for (int r = 0; r < 4; ++r) {
            int row = r0 + r;
            float dx = s_px[row] - cx, dy = s_py[row] - cy, dz = s_pz[row] - cz;
            float dd = fmaf(dx, dx, fmaf(dy, dy, dz * dz));
            float dist = sqrtf(fmaxf(dd, 1e-12f));
            float u = fminf(dist, DMAX) * tscale;
            int i = (int)u; if (i > TBL - 2) i = TBL - 2;
            float fr = u - (float)i;
            float t0 = s_tbl[i];
            sacc[ct][r] += fmaf(fr, s_tbl[i + 1] - t0, t0);
        }
    }

    // ---- softmax over 64 cols (16-lane group x 4 tiles holds each row) ----
    float inv[4];
#pragma unroll
    for (int r = 0; r < 4; ++r) {
        float m = fmaxf(fmaxf(sacc[0][r], sacc[1][r]), fmaxf(sacc[2][r], sacc[3][r]));
#pragma unroll
        for (int off = 1; off < 16; off <<= 1) m = fmaxf(m, __shfl_xor(m, off, 64));
        float e0 = __expf(sacc[0][r] - m);
        float e1 = __expf(sacc[1][r] - m);
        float e2 = __expf(sacc[2][r] - m);
        float e3 = __expf(sacc[3][r] - m);
        float ssum = e0 + e1 + e2 + e3;
#pragma unroll
        for (int off = 1; off < 16; off <<= 1) ssum += __shfl_xor(ssum, off, 64);
        inv[r] = 1.0f / ssum;
        int pb = 9216 + (r0 + r) * 72 + l16;     // P staged bf16 (denom folded later)
        u1[pb + 0]  = f2bf(e0);
        u1[pb + 16] = f2bf(e1);
        u1[pb + 32] = f2bf(e2);
        u1[pb + 48] = f2bf(e3);
    }
    __syncthreads();

    // ---- agg = (P @ V) * inv ----
    f32x4 oacc[4];
#pragma unroll
    for (int i = 0; i < 4; ++i) oacc[i] = (f32x4){0.f, 0.f, 0.f, 0.f};
    const int prow = wave * 16 + l16;
#pragma unroll
    for (int kk = 0; kk < 2; ++kk) {
        bhalf8 a = *(const bhalf8*)(&u1[9216 + prow * 72 + kk * 32 + g * 8]);
#pragma unroll
        for (int ct = 0; ct < 4; ++ct) {
            bhalf8 b = *(const bhalf8*)(&u1[4608 + (ct * 16 + l16) * 72 + kk * 32 + g * 8]);
            oacc[ct] = __builtin_amdgcn_mfma_f32_16x16x32_bf16(a, b, oacc[ct], 0, 0, 0);
        }
    }
#pragma unroll
    for (int ct = 0; ct < 4; ++ct) {
        int col = head * 64 + ct * 16 + l16;
#pragma unroll
        for (int r = 0; r < 4; ++r) {
            float v = oacc[ct][r] * inv[r];
            if (FAST) aggb[(rowbase + r0 + r) * HID + col] = f2bf(v);
            else      aggf[(rowbase + r0 + r) * HID + col] = v;
        }
    }
}

// ---- kernel 2: out = agg @ w_out + b_out + h, then LayerNorm ----
template <int FAST>
__global__ __launch_bounds__(256) void k_proj(const float* __restrict__ aggf,
                                              const short* __restrict__ aggb,
                                              const float* __restrict__ h,
                                              const short* __restrict__ woT,
                                              const float* __restrict__ b_out,
                                              const float* __restrict__ gamma,
                                              const float* __restrict__ beta,
                                              float* __restrict__ out) {
    __shared__ __align__(16) short m0[64 * 40];    // agg chunk [64][32] bf16
    __shared__ __align__(16) short m1[512 * 40];   // w_out^T chunk [512][32] bf16
    const int mol = blockIdx.x;
    const int t = threadIdx.x;
    const int wave = t >> 6, lane = t & 63;
    const int l16 = lane & 15, g = lane >> 4;
    const int rowbase = mol * 64;

    f32x4 acc[32];
#pragma unroll
    for (int i = 0; i < 32; ++i) acc[i] = (f32x4){0.f, 0.f, 0.f, 0.f};

    for (int kc = 0; kc < 16; ++kc) {
        const int kb = kc * 32;
        if (FAST) {
            int row = t >> 2, seg = t & 3;      // 64 rows x 4 int4 = 256 threads
            *(int4*)(&m0[row * 40 + seg * 8]) =
                *(const int4*)(aggb + (rowbase + row) * HID + kb + seg * 8);
        } else {
#pragma unroll
            for (int p = 0; p < 2; ++p) {
                int s = t + 256 * p;
                int row = s >> 3, seg = s & 7;
                const float4 v = *(const float4*)(aggf + (rowbase + row) * HID + kb + seg * 4);
                short4 b4;
                b4.x = f2bf(v.x); b4.y = f2bf(v.y); b4.z = f2bf(v.z); b4.w = f2bf(v.w);
                *(short4*)(&m0[row * 40 + seg * 4]) = b4;
            }
        }
#pragma unroll
        for (int p = 0; p < 8; ++p) {
            int s = t + 256 * p;
            int c = s >> 2, kq = s & 3;
            *(int4*)(&m1[c * 40 + kq * 8]) = *(const int4*)(woT + c * HID + kb + kq * 8);
        }
        __syncthreads();
        const int arow = wave * 16 + l16;
        bhalf8 a = *(const bhalf8*)(&m0[arow * 40 + g * 8]);
#pragma unroll
        for (int ct = 0; ct < 32; ++ct) {
            bhalf8 b = *(const bhalf8*)(&m1[(ct * 16 + l16) * 40 + g * 8]);
            acc[ct] = __builtin_amdgcn_mfma_f32_16x16x32_bf16(a, b, acc[ct], 0, 0, 0);
        }
        __syncthreads();
    }

    // ---- + b_out + residual, LayerNorm across 512 (16 lanes x 32 tiles) ----
    const int r0 = wave * 16 + g * 4;
    float sum[4] = {0.f, 0.f, 0.f, 0.f}, sq[4] = {0.f, 0.f, 0.f, 0.f};
#pragma unroll
    for (int ct = 0; ct < 32; ++ct) {
        int col = ct * 16 + l16;
        float bo = b_out[col];
#pragma unroll
        for (int r = 0; r < 4; ++r) {
            float v = acc[ct][r] + bo + h[(rowbase + r0 + r) * HID + col];
            acc[ct][r] = v;
            sum[r] += v;
            sq[r] = fmaf(v, v, sq[r]);
        }
    }
#pragma unroll
    for (int r = 0; r < 4; ++r) {
#pragma unroll
        for (int off = 1; off < 16; off <<= 1) {
            sum[r] += __shfl_xor(sum[r], off, 64);
            sq[r]  += __shfl_xor(sq[r], off, 64);
        }
    }
    float mean[4], rstd[4];
#pragma unroll
    for (int r = 0; r < 4; ++r) {
        mean[r] = sum[r] * (1.0f / 512.0f);
        float var = sq[r] * (1.0f / 512.0f) - mean[r] * mean[r];
        rstd[r] = rsqrtf(var + 1e-5f);
    }
#pragma unroll
    for (int ct = 0; ct < 32; ++ct) {
        int col = ct * 16 + l16;
        float ga = gamma[col], be = beta[col];
#pragma unroll
        for (int r = 0; r < 4; ++r) {
            out[(rowbase + r0 + r) * HID + col] =
                fmaf((acc[ct][r] - mean[r]) * rstd[r], ga, be);
        }
    }
}

extern "C" void kernel_launch(void* const* d_in, const int* in_sizes, int n_in,
                              void* d_out, int out_size, void* d_ws, size_t ws_size,
                              hipStream_t stream) {
    (void)in_sizes; (void)n_in; (void)out_size;
    const float* h       = (const float*)d_in[0];
    const float* pos     = (const float*)d_in[1];
    // d_in[2] = batch (unused: equal-size contiguous molecules)
    const float* centers = (const float*)d_in[3];
    const float* w_rbf   = (const float*)d_in[4];
    const float* b_rbf   = (const float*)d_in[5];
    const float* w_qkv   = (const float*)d_in[6];
    const float* b_qkv   = (const float*)d_in[7];
    const float* w_out   = (const float*)d_in[8];
    const float* b_out   = (const float*)d_in[9];
    const float* gamma   = (const float*)d_in[10];
    const float* beta    = (const float*)d_in[11];
    float* out = (float*)d_out;

    char* ws = (char*)d_ws;
    short* wqT = (short*)ws;                           // [1536][512] bf16 = 1.5 MB
    short* woT = (short*)(ws + 1572864);               // [512][512]  bf16 = 0.5 MB
    float* tbl = (float*)(ws + 2097152);               // [8][2048]   f32  = 64 KB
    short* hbf = (short*)(ws + 2162688);               // [65536][512] bf16 = 64 MB
    short* agb = (short*)(ws + 2162688 + 67108864);    // [65536][512] bf16 = 64 MB
    const size_t need = 2162688ull + 2ull * 67108864ull;
    const int fast = (ws_size >= need) ? 1 : 0;

    k_prep_w<<<256, 256, 0, stream>>>(w_qkv, w_out, wqT, woT);
    k_prep_tbl<<<64, 256, 0, stream>>>(centers, w_rbf, b_rbf, tbl);
    if (fast) {
        k_prep_h<<<16384, 256, 0, stream>>>(h, hbf);
        k_attn<1><<<8192, 256, 0, stream>>>(h, hbf, pos, b_qkv, wqT, tbl, out, agb);
        k_proj<1><<<1024, 256, 0, stream>>>(out, agb, h, woT, b_out, gamma, beta, out);
    } else {
        k_attn<0><<<8192, 256, 0, stream>>>(h, hbf, pos, b_qkv, wqT, tbl, out, agb);
        k_proj<0><<<1024, 256, 0, stream>>>(out, agb, h, woT, b_out, gamma, beta, out);
    }
}

// Round 3
// 434.461 us; speedup vs baseline: 1.5011x; 1.5011x over previous
//
#include <hip/hip_runtime.h>
#include <hip/hip_bf16.h>

// PointSelfAttention R3: decomposed pipeline with balanced LDS:MFMA tiles.
//   k_prep_w   : w_qkv/w_out -> bf16 [col][K] layouts
//   k_prep_tbl : per-head RBF bias lookup table
//   k_qkv      : GEMM M=32768(half) N=1536 K=512 -> blocked q/k/v bf16 panels (bias+scale fused)
//   k_attn     : per (mol,head): S=qk^T + bias, softmax, PV -> agg fp32 into d_out
//   k_proj     : per mol: agg @ w_out + b_out + h, LayerNorm -> d_out (in place)

#define HID 512
#define TBL 2048
#define DMAX 12.0f

typedef __attribute__((ext_vector_type(4))) float f32x4;
typedef __attribute__((ext_vector_type(8))) short bhalf8;

__device__ __forceinline__ short f2bf(float f) {
    union { float f; unsigned u; } x; x.f = f;
    unsigned u = x.u;
    unsigned r = (u + 0x7FFFu + ((u >> 16) & 1u)) >> 16;  // RNE
    return (short)r;
}

// ---- prep: transpose weights to bf16 [cols][K] ----
__global__ __launch_bounds__(256) void k_prep_w(const float* __restrict__ w_qkv,
                                                const float* __restrict__ w_out,
                                                short* __restrict__ wqT,
                                                short* __restrict__ woT) {
    __shared__ short tile[64][68];
    const int t = threadIdx.x;
    int bt = blockIdx.x;
    const float* src; short* dst; int sld, tk, tc;
    if (bt < 192) { src = w_qkv; dst = wqT; sld = 1536; tk = bt & 7; tc = bt >> 3; }
    else { int b2 = bt - 192; src = w_out; dst = woT; sld = 512; tk = b2 & 7; tc = b2 >> 3; }
#pragma unroll
    for (int p = 0; p < 4; ++p) {
        int s = t + 256 * p;
        int r = s >> 4, sg = s & 15;
        const float4 v = *(const float4*)(src + (tk * 64 + r) * sld + tc * 64 + sg * 4);
        tile[r][sg * 4 + 0] = f2bf(v.x);
        tile[r][sg * 4 + 1] = f2bf(v.y);
        tile[r][sg * 4 + 2] = f2bf(v.z);
        tile[r][sg * 4 + 3] = f2bf(v.w);
    }
    __syncthreads();
#pragma unroll
    for (int p = 0; p < 16; ++p) {
        int o = t + 256 * p;
        int c = o >> 6, k = o & 63;
        dst[(tc * 64 + c) * 512 + tk * 64 + k] = tile[k][c];
    }
}

// ---- prep: per-head bias(d) table ----
__global__ __launch_bounds__(256) void k_prep_tbl(const float* __restrict__ centers,
                                                  const float* __restrict__ w_rbf,
                                                  const float* __restrict__ b_rbf,
                                                  float* __restrict__ tbl) {
    int idx = blockIdx.x * 256 + threadIdx.x;   // 8 heads * 2048
    int hh = idx >> 11, i = idx & (TBL - 1);
    float d = (float)i * (DMAX / (float)(TBL - 1));
    float s = b_rbf[hh];
    const float invw = 1.0f / 0.0625f;          // width = (8/32)^2
#pragma unroll 4
    for (int r = 0; r < 32; ++r) {
        float tt = d - centers[r];
        s += w_rbf[r * 8 + hh] * expf(-(tt * tt) * invw);
    }
    tbl[idx] = s;
}

// ---- QKV GEMM: 128 rows x 256 cols per block, 8 waves, wave-tile 64x64 ----
// Output: qkvb[mol_local][sec][head][64 row][64 d] bf16, bias added, q pre-scaled.
__global__ __launch_bounds__(512) void k_qkv(const float* __restrict__ h,
                                             const float* __restrict__ b_qkv,
                                             const short* __restrict__ wqT,
                                             short* __restrict__ qkvb,
                                             int molbase) {
    __shared__ __align__(16) short As[128 * 40];   // 10 KB, pad 40 -> 2-way free
    __shared__ __align__(16) short Bs[256 * 40];   // 20 KB
    const int t = threadIdx.x;
    const int lane = t & 63, wave = t >> 6;
    const int l16 = lane & 15, g = lane >> 4;
    const int wrow = wave >> 2, wcol = wave & 3;   // 2 x 4 wave grid
    const int R0 = molbase * 64 + blockIdx.x * 128;
    const int C0 = blockIdx.y * 256;

    f32x4 acc[4][4];
#pragma unroll
    for (int i = 0; i < 4; ++i)
#pragma unroll
        for (int j = 0; j < 4; ++j) acc[i][j] = (f32x4){0.f, 0.f, 0.f, 0.f};

    const int arow = t >> 2, aseg = t & 3;         // A stage map
    for (int kc = 0; kc < 16; ++kc) {
        const int kb = kc * 32;
        {   // A: h fp32 -> bf16, 128x32
            const float* src = h + (R0 + arow) * HID + kb + aseg * 8;
            float4 v0 = *(const float4*)src;
            float4 v1 = *(const float4*)(src + 4);
            short s8[8];
            s8[0] = f2bf(v0.x); s8[1] = f2bf(v0.y); s8[2] = f2bf(v0.z); s8[3] = f2bf(v0.w);
            s8[4] = f2bf(v1.x); s8[5] = f2bf(v1.y); s8[6] = f2bf(v1.z); s8[7] = f2bf(v1.w);
            *(int4*)(&As[arow * 40 + aseg * 8]) = *(int4*)s8;
        }
#pragma unroll
        for (int p = 0; p < 2; ++p) {              // B: wqT bf16 copy, 256x32
            int flat = p * 512 + t;
            int col = flat >> 2, seg = flat & 3;
            *(int4*)(&Bs[col * 40 + seg * 8]) =
                *(const int4*)(wqT + (C0 + col) * HID + kb + seg * 8);
        }
        __syncthreads();
        bhalf8 af[4], bf[4];
#pragma unroll
        for (int mt = 0; mt < 4; ++mt)
            af[mt] = *(const bhalf8*)(&As[(wrow * 64 + mt * 16 + l16) * 40 + g * 8]);
#pragma unroll
        for (int nt = 0; nt < 4; ++nt)
            bf[nt] = *(const bhalf8*)(&Bs[(wcol * 64 + nt * 16 + l16) * 40 + g * 8]);
#pragma unroll
        for (int mt = 0; mt < 4; ++mt)
#pragma unroll
            for (int nt = 0; nt < 4; ++nt)
                acc[mt][nt] = __builtin_amdgcn_mfma_f32_16x16x32_bf16(af[mt], bf[nt], acc[mt][nt], 0, 0, 0);
        __syncthreads();
    }

    // epilogue: +bias, q-scale, write blocked panels
    const int sec = C0 >> 9;                       // uniform per block
    const float mul = (sec == 0) ? 0.125f : 1.0f;
#pragma unroll
    for (int nt = 0; nt < 4; ++nt) {
        int c = C0 + wcol * 64 + nt * 16 + l16;
        float bv = b_qkv[c];
        int head = (c >> 6) & 7, d = c & 63;
#pragma unroll
        for (int mt = 0; mt < 4; ++mt) {
            int rowg = R0 + wrow * 64 + mt * 16 + g * 4;
            int mol_local = (rowg >> 6) - molbase;
            short* panel = qkvb + (size_t)((mol_local * 3 + sec) * 8 + head) * 4096;
            int rloc = rowg & 63;
#pragma unroll
            for (int r = 0; r < 4; ++r)
                panel[(rloc + r) * 64 + d] = f2bf((acc[mt][nt][r] + bv) * mul);
        }
    }
}

// ---- attention: per (mol_local, head): S = q.k^T + bias, softmax, P@V ----
__global__ __launch_bounds__(256) void k_attn(const short* __restrict__ qkvb,
                                              const float* __restrict__ pos,
                                              const float* __restrict__ tbl,
                                              float* __restrict__ agg,
                                              int molbase) {
    __shared__ __align__(16) short sq[64 * 72];
    __shared__ __align__(16) short sk[64 * 72];
    __shared__ __align__(16) short svT[64 * 72];   // svT[d][key]
    __shared__ __align__(16) short sp[64 * 72];
    __shared__ float s_tbl[TBL];
    __shared__ float s_px[64], s_py[64], s_pz[64];

    const int bid = blockIdx.x;
    const int mol_local = bid >> 3, head = bid & 7;
    const int t = threadIdx.x;
    const int wave = t >> 6, lane = t & 63;
    const int l16 = lane & 15, g = lane >> 4;
    const int rowbase = (molbase + mol_local) * 64;

    const short* qp = qkvb + (size_t)((mol_local * 3 + 0) * 8 + head) * 4096;
    const short* kp = qkvb + (size_t)((mol_local * 3 + 1) * 8 + head) * 4096;
    const short* vp = qkvb + (size_t)((mol_local * 3 + 2) * 8 + head) * 4096;

#pragma unroll
    for (int p = 0; p < 2; ++p) {
        int slot = p * 256 + t;
        int row = slot >> 3, seg = slot & 7;
        *(int4*)(&sq[row * 72 + seg * 8]) = *(const int4*)(qp + slot * 8);
        *(int4*)(&sk[row * 72 + seg * 8]) = *(const int4*)(kp + slot * 8);
        int4 vv = *(const int4*)(vp + slot * 8);
        short* vs = (short*)&vv;
#pragma unroll
        for (int j = 0; j < 8; ++j) svT[(seg * 8 + j) * 72 + row] = vs[j];
    }
    for (int i = t; i < TBL; i += 256) s_tbl[i] = tbl[head * TBL + i];
    if (t < 64) {
        s_px[t] = pos[(rowbase + t) * 3 + 0];
        s_py[t] = pos[(rowbase + t) * 3 + 1];
        s_pz[t] = pos[(rowbase + t) * 3 + 2];
    }
    __syncthreads();

    // S = q_scaled . k^T  (wave owns rows wave*16..+15)
    f32x4 sacc[4];
#pragma unroll
    for (int i = 0; i < 4; ++i) sacc[i] = (f32x4){0.f, 0.f, 0.f, 0.f};
    const int srow = wave * 16 + l16;
#pragma unroll
    for (int kk = 0; kk < 2; ++kk) {
        bhalf8 a = *(const bhalf8*)(&sq[srow * 72 + kk * 32 + g * 8]);
#pragma unroll
        for (int ct = 0; ct < 4; ++ct) {
            bhalf8 b = *(const bhalf8*)(&sk[(ct * 16 + l16) * 72 + kk * 32 + g * 8]);
            sacc[ct] = __builtin_amdgcn_mfma_f32_16x16x32_bf16(a, b, sacc[ct], 0, 0, 0);
        }
    }

    // + RBF bias (table lookup)
    const int r0 = wave * 16 + g * 4;
    const float tscale = (float)(TBL - 1) / DMAX;
#pragma unroll
    for (int ct = 0; ct < 4; ++ct) {
        int col = ct * 16 + l16;
        float cx = s_px[col], cy = s_py[col], cz = s_pz[col];
#pragma unroll
        for (int r = 0; r < 4; ++r) {
            int row = r0 + r;
            float dx = s_px[row] - cx, dy = s_py[row] - cy, dz = s_pz[row] - cz;
            float dd = fmaf(dx, dx, fmaf(dy, dy, dz * dz));
            float dist = sqrtf(fmaxf(dd, 1e-12f));
            float u = fminf(dist, DMAX) * tscale;
            int i = (int)u; if (i > TBL - 2) i = TBL - 2;
            float fr = u - (float)i;
            float t0 = s_tbl[i];
            sacc[ct][r] += fmaf(fr, s_tbl[i + 1] - t0, t0);
        }
    }

    // softmax rows (16-lane groups hold full rows across 4 tiles)
    float inv[4];
#pragma unroll
    for (int r = 0; r < 4; ++r) {
        float m = fmaxf(fmaxf(sacc[0][r], sacc[1][r]), fmaxf(sacc[2][r], sacc[3][r]));
#pragma unroll
        for (int off = 1; off < 16; off <<= 1) m = fmaxf(m, __shfl_xor(m, off, 64));
        float e0 = __expf(sacc[0][r] - m);
        float e1 = __expf(sacc[1][r] - m);
        float e2 = __expf(sacc[2][r] - m);
        float e3 = __expf(sacc[3][r] - m);
        float ssum = e0 + e1 + e2 + e3;
#pragma unroll
        for (int off = 1; off < 16; off <<= 1) ssum += __shfl_xor(ssum, off, 64);
        inv[r] = 1.0f / ssum;
        int pb = (r0 + r) * 72 + l16;
        sp[pb + 0]  = f2bf(e0);
        sp[pb + 16] = f2bf(e1);
        sp[pb + 32] = f2bf(e2);
        sp[pb + 48] = f2bf(e3);
    }
    __syncthreads();

    // agg = (P @ V) * inv
    f32x4 oacc[4];
#pragma unroll
    for (int i = 0; i < 4; ++i) oacc[i] = (f32x4){0.f, 0.f, 0.f, 0.f};
#pragma unroll
    for (int kk = 0; kk < 2; ++kk) {
        bhalf8 a = *(const bhalf8*)(&sp[srow * 72 + kk * 32 + g * 8]);
#pragma unroll
        for (int ct = 0; ct < 4; ++ct) {
            bhalf8 b = *(const bhalf8*)(&svT[(ct * 16 + l16) * 72 + kk * 32 + g * 8]);
            oacc[ct] = __builtin_amdgcn_mfma_f32_16x16x32_bf16(a, b, oacc[ct], 0, 0, 0);
        }
    }
#pragma unroll
    for (int ct = 0; ct < 4; ++ct) {
        int col = head * 64 + ct * 16 + l16;
#pragma unroll
        for (int r = 0; r < 4; ++r)
            agg[(rowbase + r0 + r) * HID + col] = oacc[ct][r] * inv[r];
    }
}

// ---- out proj + residual + LayerNorm: per mol, 8 waves, wave-tile 64x64 ----
__global__ __launch_bounds__(512) void k_proj(const float* __restrict__ aggf,
                                              const float* __restrict__ h,
                                              const short* __restrict__ woT,
                                              const float* __restrict__ b_out,
                                              const float* __restrict__ gamma,
                                              const float* __restrict__ beta,
                                              float* __restrict__ out) {
    __shared__ __align__(16) short As[64 * 40];    // 5 KB
    __shared__ __align__(16) short Bs[512 * 40];   // 40 KB
    __shared__ float red[64 * 16];                 // [row][wave*2]
    __shared__ float mr[64 * 2];
    const int mol = blockIdx.x;
    const int t = threadIdx.x;
    const int wave = t >> 6, lane = t & 63;
    const int l16 = lane & 15, g = lane >> 4;
    const int rowbase = mol * 64;

    f32x4 acc[4][4];
#pragma unroll
    for (int i = 0; i < 4; ++i)
#pragma unroll
        for (int j = 0; j < 4; ++j) acc[i][j] = (f32x4){0.f, 0.f, 0.f, 0.f};

    for (int kc = 0; kc < 16; ++kc) {
        const int kb = kc * 32;
        if (t < 256) {                             // A: agg fp32 -> bf16, 64x32
            int row = t >> 2, seg = t & 3;
            const float* src = aggf + (rowbase + row) * HID + kb + seg * 8;
            float4 v0 = *(const float4*)src;
            float4 v1 = *(const float4*)(src + 4);
            short s8[8];
            s8[0] = f2bf(v0.x); s8[1] = f2bf(v0.y); s8[2] = f2bf(v0.z); s8[3] = f2bf(v0.w);
            s8[4] = f2bf(v1.x); s8[5] = f2bf(v1.y); s8[6] = f2bf(v1.z); s8[7] = f2bf(v1.w);
            *(int4*)(&As[row * 40 + seg * 8]) = *(int4*)s8;
        }
#pragma unroll
        for (int p = 0; p < 4; ++p) {              // B: woT, 512x32
            int flat = p * 512 + t;
            int col = flat >> 2, seg = flat & 3;
            *(int4*)(&Bs[col * 40 + seg * 8]) =
                *(const int4*)(woT + col * HID + kb + seg * 8);
        }
        __syncthreads();
        bhalf8 af[4], bf[4];
#pragma unroll
        for (int mt = 0; mt < 4; ++mt)
            af[mt] = *(const bhalf8*)(&As[(mt * 16 + l16) * 40 + g * 8]);
#pragma unroll
        for (int nt = 0; nt < 4; ++nt)
            bf[nt] = *(const bhalf8*)(&Bs[(wave * 64 + nt * 16 + l16) * 40 + g * 8]);
#pragma unroll
        for (int mt = 0; mt < 4; ++mt)
#pragma unroll
            for (int nt = 0; nt < 4; ++nt)
                acc[mt][nt] = __builtin_amdgcn_mfma_f32_16x16x32_bf16(af[mt], bf[nt], acc[mt][nt], 0, 0, 0);
        __syncthreads();
    }

    // + b_out + residual; per-row partial sums over this wave's 64 cols
#pragma unroll
    for (int mt = 0; mt < 4; ++mt) {
        float s = 0.f, q = 0.f;
#pragma unroll
        for (int r = 0; r < 4; ++r) {
            int row = mt * 16 + g * 4 + r;
            float rs = 0.f, rq = 0.f;
#pragma unroll
            for (int nt = 0; nt < 4; ++nt) {
                int col = wave * 64 + nt * 16 + l16;
                float v = acc[mt][nt][r] + b_out[col] + h[(rowbase + row) * HID + col];
                acc[mt][nt][r] = v;
                rs += v;
                rq = fmaf(v, v, rq);
            }
#pragma unroll
            for (int off = 1; off < 16; off <<= 1) {
                rs += __shfl_xor(rs, off, 16);
                rq += __shfl_xor(rq, off, 16);
            }
            if (l16 == 0) {
                red[row * 16 + wave * 2 + 0] = rs;
                red[row * 16 + wave * 2 + 1] = rq;
            }
            s = rs; q = rq;  // keep alive (unused)
        }
        (void)s; (void)q;
    }
    __syncthreads();
    if (t < 64) {
        float s = 0.f, q = 0.f;
#pragma unroll
        for (int w = 0; w < 8; ++w) {
            s += red[t * 16 + w * 2 + 0];
            q += red[t * 16 + w * 2 + 1];
        }
        float mean = s * (1.0f / 512.0f);
        float var = q * (1.0f / 512.0f) - mean * mean;
        mr[t * 2 + 0] = mean;
        mr[t * 2 + 1] = rsqrtf(var + 1e-5f);
    }
    __syncthreads();
#pragma unroll
    for (int mt = 0; mt < 4; ++mt)
#pragma unroll
        for (int r = 0; r < 4; ++r) {
            int row = mt * 16 + g * 4 + r;
            float mean = mr[row * 2 + 0], rstd = mr[row * 2 + 1];
#pragma unroll
            for (int nt = 0; nt < 4; ++nt) {
                int col = wave * 64 + nt * 16 + l16;
                out[(rowbase + row) * HID + col] =
                    fmaf((acc[mt][nt][r] - mean) * rstd, gamma[col], beta[col]);
            }
        }
}

extern "C" void kernel_launch(void* const* d_in, const int* in_sizes, int n_in,
                              void* d_out, int out_size, void* d_ws, size_t ws_size,
                              hipStream_t stream) {
    (void)in_sizes; (void)n_in; (void)out_size; (void)ws_size;
    const float* h       = (const float*)d_in[0];
    const float* pos     = (const float*)d_in[1];
    // d_in[2] = batch (unused: equal-size contiguous molecules)
    const float* centers = (const float*)d_in[3];
    const float* w_rbf   = (const float*)d_in[4];
    const float* b_rbf   = (const float*)d_in[5];
    const float* w_qkv   = (const float*)d_in[6];
    const float* b_qkv   = (const float*)d_in[7];
    const float* w_out   = (const float*)d_in[8];
    const float* b_out   = (const float*)d_in[9];
    const float* gamma   = (const float*)d_in[10];
    const float* beta    = (const float*)d_in[11];
    float* out = (float*)d_out;

    char* ws = (char*)d_ws;
    short* wqT  = (short*)ws;                      // [1536][512] bf16 = 1.5 MB
    short* woT  = (short*)(ws + 1572864);          // [512][512]  bf16 = 0.5 MB
    float* tbl  = (float*)(ws + 2097152);          // [8][2048]   f32  = 64 KB
    short* qkvb = (short*)(ws + 2162688);          // [512 mol][3][8][64][64] bf16 = 96 MB

    k_prep_w<<<256, 256, 0, stream>>>(w_qkv, w_out, wqT, woT);
    k_prep_tbl<<<64, 256, 0, stream>>>(centers, w_rbf, b_rbf, tbl);
    for (int half = 0; half < 2; ++half) {
        int molbase = half * 512;
        k_qkv<<<dim3(256, 6), 512, 0, stream>>>(h, b_qkv, wqT, qkvb, molbase);
        k_attn<<<4096, 256, 0, stream>>>(qkvb, pos, tbl, out, molbase);
    }
    k_proj<<<1024, 512, 0, stream>>>(out, h, woT, b_out, gamma, beta, out);
}

// Round 4
// 390.277 us; speedup vs baseline: 1.6711x; 1.1132x over previous
//
#include <hip/hip_runtime.h>
#include <hip/hip_bf16.h>

// PointSelfAttention R4:
//   k_prep_w   : w_qkv/w_out -> bf16 [col][K] layouts
//   k_prep_tbl : per-head RBF bias lookup table
//   k_qkv      : GEMM -> blocked q/k/v bf16 panels (bias+scale fused)  [unchanged]
//   k_attn     : S=qk^T + bias, softmax, PV -> agg fp32 in d_out  [svT XOR-swizzle]
//   k_proj     : M=128 blocks, wave-tile 64x128, register-prefetch pipeline + fused LN

#define HID 512
#define TBL 2048
#define DMAX 12.0f

typedef __attribute__((ext_vector_type(4))) float f32x4;
typedef __attribute__((ext_vector_type(8))) short bhalf8;

__device__ __forceinline__ short f2bf(float f) {
    union { float f; unsigned u; } x; x.f = f;
    unsigned u = x.u;
    unsigned r = (u + 0x7FFFu + ((u >> 16) & 1u)) >> 16;  // RNE
    return (short)r;
}

// ---- prep: transpose weights to bf16 [cols][K] ----
__global__ __launch_bounds__(256) void k_prep_w(const float* __restrict__ w_qkv,
                                                const float* __restrict__ w_out,
                                                short* __restrict__ wqT,
                                                short* __restrict__ woT) {
    __shared__ short tile[64][68];
    const int t = threadIdx.x;
    int bt = blockIdx.x;
    const float* src; short* dst; int sld, tk, tc;
    if (bt < 192) { src = w_qkv; dst = wqT; sld = 1536; tk = bt & 7; tc = bt >> 3; }
    else { int b2 = bt - 192; src = w_out; dst = woT; sld = 512; tk = b2 & 7; tc = b2 >> 3; }
#pragma unroll
    for (int p = 0; p < 4; ++p) {
        int s = t + 256 * p;
        int r = s >> 4, sg = s & 15;
        const float4 v = *(const float4*)(src + (tk * 64 + r) * sld + tc * 64 + sg * 4);
        tile[r][sg * 4 + 0] = f2bf(v.x);
        tile[r][sg * 4 + 1] = f2bf(v.y);
        tile[r][sg * 4 + 2] = f2bf(v.z);
        tile[r][sg * 4 + 3] = f2bf(v.w);
    }
    __syncthreads();
#pragma unroll
    for (int p = 0; p < 16; ++p) {
        int o = t + 256 * p;
        int c = o >> 6, k = o & 63;
        dst[(tc * 64 + c) * 512 + tk * 64 + k] = tile[k][c];
    }
}

// ---- prep: per-head bias(d) table ----
__global__ __launch_bounds__(256) void k_prep_tbl(const float* __restrict__ centers,
                                                  const float* __restrict__ w_rbf,
                                                  const float* __restrict__ b_rbf,
                                                  float* __restrict__ tbl) {
    int idx = blockIdx.x * 256 + threadIdx.x;   // 8 heads * 2048
    int hh = idx >> 11, i = idx & (TBL - 1);
    float d = (float)i * (DMAX / (float)(TBL - 1));
    float s = b_rbf[hh];
    const float invw = 1.0f / 0.0625f;          // width = (8/32)^2
#pragma unroll 4
    for (int r = 0; r < 32; ++r) {
        float tt = d - centers[r];
        s += w_rbf[r * 8 + hh] * expf(-(tt * tt) * invw);
    }
    tbl[idx] = s;
}

// ---- QKV GEMM: 128 rows x 256 cols per block, 8 waves, wave-tile 64x64 ----
__global__ __launch_bounds__(512) void k_qkv(const float* __restrict__ h,
                                             const float* __restrict__ b_qkv,
                                             const short* __restrict__ wqT,
                                             short* __restrict__ qkvb,
                                             int molbase) {
    __shared__ __align__(16) short As[128 * 40];
    __shared__ __align__(16) short Bs[256 * 40];
    const int t = threadIdx.x;
    const int lane = t & 63, wave = t >> 6;
    const int l16 = lane & 15, g = lane >> 4;
    const int wrow = wave >> 2, wcol = wave & 3;   // 2 x 4 wave grid
    const int R0 = molbase * 64 + blockIdx.x * 128;
    const int C0 = blockIdx.y * 256;

    f32x4 acc[4][4];
#pragma unroll
    for (int i = 0; i < 4; ++i)
#pragma unroll
        for (int j = 0; j < 4; ++j) acc[i][j] = (f32x4){0.f, 0.f, 0.f, 0.f};

    const int arow = t >> 2, aseg = t & 3;
    for (int kc = 0; kc < 16; ++kc) {
        const int kb = kc * 32;
        {   // A: h fp32 -> bf16, 128x32
            const float* src = h + (R0 + arow) * HID + kb + aseg * 8;
            float4 v0 = *(const float4*)src;
            float4 v1 = *(const float4*)(src + 4);
            short s8[8];
            s8[0] = f2bf(v0.x); s8[1] = f2bf(v0.y); s8[2] = f2bf(v0.z); s8[3] = f2bf(v0.w);
            s8[4] = f2bf(v1.x); s8[5] = f2bf(v1.y); s8[6] = f2bf(v1.z); s8[7] = f2bf(v1.w);
            *(int4*)(&As[arow * 40 + aseg * 8]) = *(int4*)s8;
        }
#pragma unroll
        for (int p = 0; p < 2; ++p) {              // B: wqT bf16 copy, 256x32
            int flat = p * 512 + t;
            int col = flat >> 2, seg = flat & 3;
            *(int4*)(&Bs[col * 40 + seg * 8]) =
                *(const int4*)(wqT + (C0 + col) * HID + kb + seg * 8);
        }
        __syncthreads();
        bhalf8 af[4], bf[4];
#pragma unroll
        for (int mt = 0; mt < 4; ++mt)
            af[mt] = *(const bhalf8*)(&As[(wrow * 64 + mt * 16 + l16) * 40 + g * 8]);
#pragma unroll
        for (int nt = 0; nt < 4; ++nt)
            bf[nt] = *(const bhalf8*)(&Bs[(wcol * 64 + nt * 16 + l16) * 40 + g * 8]);
#pragma unroll
        for (int mt = 0; mt < 4; ++mt)
#pragma unroll
            for (int nt = 0; nt < 4; ++nt)
                acc[mt][nt] = __builtin_amdgcn_mfma_f32_16x16x32_bf16(af[mt], bf[nt], acc[mt][nt], 0, 0, 0);
        __syncthreads();
    }

    const int sec = C0 >> 9;
    const float mul = (sec == 0) ? 0.125f : 1.0f;
#pragma unroll
    for (int nt = 0; nt < 4; ++nt) {
        int c = C0 + wcol * 64 + nt * 16 + l16;
        float bv = b_qkv[c];
        int head = (c >> 6) & 7, d = c & 63;
#pragma unroll
        for (int mt = 0; mt < 4; ++mt) {
            int rowg = R0 + wrow * 64 + mt * 16 + g * 4;
            int mol_local = (rowg >> 6) - molbase;
            short* panel = qkvb + (size_t)((mol_local * 3 + sec) * 8 + head) * 4096;
            int rloc = rowg & 63;
#pragma unroll
            for (int r = 0; r < 4; ++r)
                panel[(rloc + r) * 64 + d] = f2bf((acc[mt][nt][r] + bv) * mul);
        }
    }
}

// ---- attention: per (mol_local, head): S = q.k^T + bias, softmax, P@V ----
__global__ __launch_bounds__(256) void k_attn(const short* __restrict__ qkvb,
                                              const float* __restrict__ pos,
                                              const float* __restrict__ tbl,
                                              float* __restrict__ agg,
                                              int molbase) {
    __shared__ __align__(16) short sq[64 * 72];
    __shared__ __align__(16) short sk[64 * 72];
    __shared__ __align__(16) short svT[64 * 72];   // svT[d][key], key XOR-swizzled
    __shared__ __align__(16) short sp[64 * 72];
    __shared__ float s_tbl[TBL];
    __shared__ float s_px[64], s_py[64], s_pz[64];

    const int bid = blockIdx.x;
    const int mol_local = bid >> 3, head = bid & 7;
    const int t = threadIdx.x;
    const int wave = t >> 6, lane = t & 63;
    const int l16 = lane & 15, g = lane >> 4;
    const int rowbase = (molbase + mol_local) * 64;

    const short* qp = qkvb + (size_t)((mol_local * 3 + 0) * 8 + head) * 4096;
    const short* kp = qkvb + (size_t)((mol_local * 3 + 1) * 8 + head) * 4096;
    const short* vp = qkvb + (size_t)((mol_local * 3 + 2) * 8 + head) * 4096;

#pragma unroll
    for (int p = 0; p < 2; ++p) {
        int slot = p * 256 + t;
        int row = slot >> 3, seg = slot & 7;
        *(int4*)(&sq[row * 72 + seg * 8]) = *(const int4*)(qp + slot * 8);
        *(int4*)(&sk[row * 72 + seg * 8]) = *(const int4*)(kp + slot * 8);
        int4 vv = *(const int4*)(vp + slot * 8);
        short* vs = (short*)&vv;
        // svT[d][key]: addr = d*72 + (key&7) + 8*(((key>>3) ^ (d>>3)) & 7); d = seg*8+j
#pragma unroll
        for (int j = 0; j < 8; ++j)
            svT[(seg * 8 + j) * 72 + (row & 7) + (((row >> 3) ^ seg) & 7) * 8] = vs[j];
    }
    for (int i = t; i < TBL; i += 256) s_tbl[i] = tbl[head * TBL + i];
    if (t < 64) {
        s_px[t] = pos[(rowbase + t) * 3 + 0];
        s_py[t] = pos[(rowbase + t) * 3 + 1];
        s_pz[t] = pos[(rowbase + t) * 3 + 2];
    }
    __syncthreads();

    // S = q_scaled . k^T
    f32x4 sacc[4];
#pragma unroll
    for (int i = 0; i < 4; ++i) sacc[i] = (f32x4){0.f, 0.f, 0.f, 0.f};
    const int srow = wave * 16 + l16;
#pragma unroll
    for (int kk = 0; kk < 2; ++kk) {
        bhalf8 a = *(const bhalf8*)(&sq[srow * 72 + kk * 32 + g * 8]);
#pragma unroll
        for (int ct = 0; ct < 4; ++ct) {
            bhalf8 b = *(const bhalf8*)(&sk[(ct * 16 + l16) * 72 + kk * 32 + g * 8]);
            sacc[ct] = __builtin_amdgcn_mfma_f32_16x16x32_bf16(a, b, sacc[ct], 0, 0, 0);
        }
    }

    // + RBF bias (table lookup)
    const int r0 = wave * 16 + g * 4;
    const float tscale = (float)(TBL - 1) / DMAX;
#pragma unroll
    for (int ct = 0; ct < 4; ++ct) {
        int col = ct * 16 + l16;
        float cx = s_px[col], cy = s_py[col], cz = s_pz[col];
#pragma unroll
        for (int r = 0; r < 4; ++r) {
            int row = r0 + r;
            float dx = s_px[row] - cx, dy = s_py[row] - cy, dz = s_pz[row] - cz;
            float dd = fmaf(dx, dx, fmaf(dy, dy, dz * dz));
            float dist = sqrtf(fmaxf(dd, 1e-12f));
            float u = fminf(dist, DMAX) * tscale;
            int i = (int)u; if (i > TBL - 2) i = TBL - 2;
            float fr = u - (float)i;
            float t0 = s_tbl[i];
            sacc[ct][r] += fmaf(fr, s_tbl[i + 1] - t0, t0);
        }
    }

    // softmax rows
    float inv[4];
#pragma unroll
    for (int r = 0; r < 4; ++r) {
        float m = fmaxf(fmaxf(sacc[0][r], sacc[1][r]), fmaxf(sacc[2][r], sacc[3][r]));
#pragma unroll
        for (int off = 1; off < 16; off <<= 1) m = fmaxf(m, __shfl_xor(m, off, 64));
        float e0 = __expf(sacc[0][r] - m);
        float e1 = __expf(sacc[1][r] - m);
        float e2 = __expf(sacc[2][r] - m);
        float e3 = __expf(sacc[3][r] - m);
        float ssum = e0 + e1 + e2 + e3;
#pragma unroll
        for (int off = 1; off < 16; off <<= 1) ssum += __shfl_xor(ssum, off, 64);
        inv[r] = 1.0f / ssum;
        int pb = (r0 + r) * 72 + l16;
        sp[pb + 0]  = f2bf(e0);
        sp[pb + 16] = f2bf(e1);
        sp[pb + 32] = f2bf(e2);
        sp[pb + 48] = f2bf(e3);
    }
    __syncthreads();

    // agg = (P @ V) * inv  -- svT read with matching swizzle
    f32x4 oacc[4];
#pragma unroll
    for (int i = 0; i < 4; ++i) oacc[i] = (f32x4){0.f, 0.f, 0.f, 0.f};
#pragma unroll
    for (int kk = 0; kk < 2; ++kk) {
        bhalf8 a = *(const bhalf8*)(&sp[srow * 72 + kk * 32 + g * 8]);
#pragma unroll
        for (int ct = 0; ct < 4; ++ct) {
            int drow = ct * 16 + l16;
            bhalf8 b = *(const bhalf8*)(&svT[drow * 72 + (((kk * 4 + g) ^ (drow >> 3)) & 7) * 8]);
            oacc[ct] = __builtin_amdgcn_mfma_f32_16x16x32_bf16(a, b, oacc[ct], 0, 0, 0);
        }
    }
#pragma unroll
    for (int ct = 0; ct < 4; ++ct) {
        int col = head * 64 + ct * 16 + l16;
#pragma unroll
        for (int r = 0; r < 4; ++r)
            agg[(rowbase + r0 + r) * HID + col] = oacc[ct][r] * inv[r];
    }
}

// ---- out proj + residual + LayerNorm: 2 mols (M=128), 8 waves, wave-tile 64x128,
//      register-prefetch double-buffer ----
__global__ __launch_bounds__(512) void k_proj(const float* __restrict__ aggf,
                                              const float* __restrict__ h,
                                              const short* __restrict__ woT,
                                              const float* __restrict__ b_out,
                                              const float* __restrict__ gamma,
                                              const float* __restrict__ beta,
                                              float* __restrict__ out) {
    __shared__ __align__(16) short As[128 * 40];   // 10 KB
    __shared__ __align__(16) short Bs[512 * 40];   // 40 KB
    __shared__ float red[128 * 8];                 // [row][wcol*2]
    __shared__ float mr[128 * 2];
    const int t = threadIdx.x;
    const int wave = t >> 6, lane = t & 63;
    const int l16 = lane & 15, g = lane >> 4;
    const int wrow = wave >> 2, wcol = wave & 3;   // 2 x 4 wave grid
    const int rowbase = blockIdx.x * 128;

    f32x4 acc[4][8];
#pragma unroll
    for (int i = 0; i < 4; ++i)
#pragma unroll
        for (int j = 0; j < 8; ++j) acc[i][j] = (f32x4){0.f, 0.f, 0.f, 0.f};

    const int arow = t >> 2, aseg = t & 3;
    int4 pA, pB0, pB1, pB2, pB3;
    const int bcol = t >> 2, bseg = t & 3;         // pBp covers col bcol + p*128

#define LOADA(kc) {                                                              \
        const float* src = aggf + (rowbase + arow) * HID + (kc) * 32 + aseg * 8; \
        float4 v0 = *(const float4*)src;                                         \
        float4 v1 = *(const float4*)(src + 4);                                   \
        short s8[8];                                                             \
        s8[0] = f2bf(v0.x); s8[1] = f2bf(v0.y); s8[2] = f2bf(v0.z); s8[3] = f2bf(v0.w); \
        s8[4] = f2bf(v1.x); s8[5] = f2bf(v1.y); s8[6] = f2bf(v1.z); s8[7] = f2bf(v1.w); \
        pA = *(int4*)s8; }
#define LOADB(kc) {                                                              \
        pB0 = *(const int4*)(woT + (bcol +   0) * HID + (kc) * 32 + bseg * 8);   \
        pB1 = *(const int4*)(woT + (bcol + 128) * HID + (kc) * 32 + bseg * 8);   \
        pB2 = *(const int4*)(woT + (bcol + 256) * HID + (kc) * 32 + bseg * 8);   \
        pB3 = *(const int4*)(woT + (bcol + 384) * HID + (kc) * 32 + bseg * 8); }
#define STAGE() {                                                                \
        *(int4*)(&As[arow * 40 + aseg * 8]) = pA;                                \
        *(int4*)(&Bs[(bcol +   0) * 40 + bseg * 8]) = pB0;                       \
        *(int4*)(&Bs[(bcol + 128) * 40 + bseg * 8]) = pB1;                       \
        *(int4*)(&Bs[(bcol + 256) * 40 + bseg * 8]) = pB2;                       \
        *(int4*)(&Bs[(bcol + 384) * 40 + bseg * 8]) = pB3; }

    LOADA(0); LOADB(0); STAGE(); __syncthreads();
    for (int kc = 0; kc < 16; ++kc) {
        if (kc < 15) { LOADA(kc + 1); LOADB(kc + 1); }
        bhalf8 af[4], bf[8];
#pragma unroll
        for (int mt = 0; mt < 4; ++mt)
            af[mt] = *(const bhalf8*)(&As[(wrow * 64 + mt * 16 + l16) * 40 + g * 8]);
#pragma unroll
        for (int nt = 0; nt < 8; ++nt)
            bf[nt] = *(const bhalf8*)(&Bs[(wcol * 128 + nt * 16 + l16) * 40 + g * 8]);
#pragma unroll
        for (int mt = 0; mt < 4; ++mt)
#pragma unroll
            for (int nt = 0; nt < 8; ++nt)
                acc[mt][nt] = __builtin_amdgcn_mfma_f32_16x16x32_bf16(af[mt], bf[nt], acc[mt][nt], 0, 0, 0);
        if (kc < 15) {
            __syncthreads();
            STAGE();
            __syncthreads();
        }
    }
#undef LOADA
#undef LOADB
#undef STAGE

    // + b_out + residual; per-row partials over this wave's 128 cols
#pragma unroll
    for (int mt = 0; mt < 4; ++mt) {
#pragma unroll
        for (int r = 0; r < 4; ++r) {
            int row = wrow * 64 + mt * 16 + g * 4 + r;
            float rs = 0.f, rq = 0.f;
#pragma unroll
            for (int nt = 0; nt < 8; ++nt) {
                int col = wcol * 128 + nt * 16 + l16;
                float v = acc[mt][nt][r] + b_out[col] + h[(rowbase + row) * HID + col];
                acc[mt][nt][r] = v;
                rs += v;
                rq = fmaf(v, v, rq);
            }
#pragma unroll
            for (int off = 1; off < 16; off <<= 1) {
                rs += __shfl_xor(rs, off, 64);
                rq += __shfl_xor(rq, off, 64);
            }
            if (l16 == 0) {
                red[row * 8 + wcol * 2 + 0] = rs;
                red[row * 8 + wcol * 2 + 1] = rq;
            }
        }
    }
    __syncthreads();
    if (t < 128) {
        float s = red[t * 8 + 0] + red[t * 8 + 2] + red[t * 8 + 4] + red[t * 8 + 6];
        float q = red[t * 8 + 1] + red[t * 8 + 3] + red[t * 8 + 5] + red[t * 8 + 7];
        float mean = s * (1.0f / 512.0f);
        float var = q * (1.0f / 512.0f) - mean * mean;
        mr[t * 2 + 0] = mean;
        mr[t * 2 + 1] = rsqrtf(var + 1e-5f);
    }
    __syncthreads();
#pragma unroll
    for (int mt = 0; mt < 4; ++mt)
#pragma unroll
        for (int r = 0; r < 4; ++r) {
            int row = wrow * 64 + mt * 16 + g * 4 + r;
            float mean = mr[row * 2 + 0], rstd = mr[row * 2 + 1];
#pragma unroll
            for (int nt = 0; nt < 8; ++nt) {
                int col = wcol * 128 + nt * 16 + l16;
                out[(rowbase + row) * HID + col] =
                    fmaf((acc[mt][nt][r] - mean) * rstd, gamma[col], beta[col]);
            }
        }
}

extern "C" void kernel_launch(void* const* d_in, const int* in_sizes, int n_in,
                              void* d_out, int out_size, void* d_ws, size_t ws_size,
                              hipStream_t stream) {
    (void)in_sizes; (void)n_in; (void)out_size; (void)ws_size;
    const float* h       = (const float*)d_in[0];
    const float* pos     = (const float*)d_in[1];
    // d_in[2] = batch (unused: equal-size contiguous molecules)
    const float* centers = (const float*)d_in[3];
    const float* w_rbf   = (const float*)d_in[4];
    const float* b_rbf   = (const float*)d_in[5];
    const float* w_qkv   = (const float*)d_in[6];
    const float* b_qkv   = (const float*)d_in[7];
    const float* w_out   = (const float*)d_in[8];
    const float* b_out   = (const float*)d_in[9];
    const float* gamma   = (const float*)d_in[10];
    const float* beta    = (const float*)d_in[11];
    float* out = (float*)d_out;

    char* ws = (char*)d_ws;
    short* wqT  = (short*)ws;                      // [1536][512] bf16 = 1.5 MB
    short* woT  = (short*)(ws + 1572864);          // [512][512]  bf16 = 0.5 MB
    float* tbl  = (float*)(ws + 2097152);          // [8][2048]   f32  = 64 KB
    short* qkvb = (short*)(ws + 2162688);          // [512 mol][3][8][64][64] bf16 = 96 MB

    k_prep_w<<<256, 256, 0, stream>>>(w_qkv, w_out, wqT, woT);
    k_prep_tbl<<<64, 256, 0, stream>>>(centers, w_rbf, b_rbf, tbl);
    for (int half = 0; half < 2; ++half) {
        int molbase = half * 512;
        k_qkv<<<dim3(256, 6), 512, 0, stream>>>(h, b_qkv, wqT, qkvb, molbase);
        k_attn<<<4096, 256, 0, stream>>>(qkvb, pos, tbl, out, molbase);
    }
    k_proj<<<512, 512, 0, stream>>>(out, h, woT, b_out, gamma, beta, out);
}